// Round 12
// baseline (1198.058 us; speedup 1.0000x reference)
//
#include <hip/hip_runtime.h>
#include <hip/hip_bf16.h>
#include <math.h>

#define D_MODEL 2048
#define N_QUERY 4
#define N_HEAD  8
#define D_HEAD  64
#define D_KV    512
#define BATCH   2
#define SEQ     2048
#define BS      (BATCH*SEQ)      /* 4096 */
#define MROWS   (BS*N_QUERY)     /* 16384 */
#define NQKV    3072             /* fused Q|K|V gemm width */

typedef __attribute__((ext_vector_type(8)))  short bf16x8;
typedef __attribute__((ext_vector_type(4)))  float f32x4;
typedef __attribute__((ext_vector_type(16))) float f32x16;
typedef unsigned short u16;
typedef unsigned int   u32;

union Frag { bf16x8 v; u32 w[4]; };

__device__ __forceinline__ f32x4 mfma16(bf16x8 a, bf16x8 b, f32x4 c) {
    return __builtin_amdgcn_mfma_f32_16x16x32_bf16(a, b, c, 0, 0, 0);
}
__device__ __forceinline__ f32x16 mfma32(bf16x8 a, bf16x8 b, f32x16 c) {
    return __builtin_amdgcn_mfma_f32_32x32x16_bf16(a, b, c, 0, 0, 0);
}
__device__ __forceinline__ u16 f32_to_bf16(float f) {
    u32 u = __float_as_uint(f);
    u32 r = (u + 0x7fffu + ((u >> 16) & 1u)) >> 16;   // RTNE
    return (u16)r;
}
__device__ __forceinline__ float bf16_to_f32(u16 h) {
    return __uint_as_float(((u32)h) << 16);
}
__device__ __forceinline__ u32 cvt_pk_bf16(float lo, float hi) {
    u32 r;
    asm volatile("v_cvt_pk_bf16_f32 %0, %1, %2" : "=v"(r) : "v"(lo), "v"(hi));
    return r;
}
// exp2 via BUILTIN: compiler must see the TRANS op for hazard waits (r8 lesson)
__device__ __forceinline__ float exp2_fast(float x) {
#if __has_builtin(__builtin_amdgcn_exp2f)
    return __builtin_amdgcn_exp2f(x);
#else
    return exp2f(x);
#endif
}
__device__ __forceinline__ void load_lds16(const void* g, void* l) {
    using GP = const __attribute__((address_space(1))) unsigned char*;
    using LP = __attribute__((address_space(3))) unsigned char*;
    __builtin_amdgcn_global_load_lds(
        reinterpret_cast<GP>(reinterpret_cast<uintptr_t>(g)),
        reinterpret_cast<LP>(reinterpret_cast<uintptr_t>(l)), 16, 0, 0);
}

// ---------------------------------------------------------------------------
// prep: blocks [0,1024) x-cast, [1024,1536) Wq, [1536,1792) Wk, [1792,2048)
// Wv, [2048,2304) memory f32 -> memT bf16 transposed.
// ---------------------------------------------------------------------------
__global__ __launch_bounds__(256) void prep(const float* __restrict__ x,   u16* __restrict__ xb,
                                            const float* __restrict__ Wq,  u16* __restrict__ wq,
                                            const float* __restrict__ Wk,  u16* __restrict__ wk,
                                            const float* __restrict__ Wv,  u16* __restrict__ wv,
                                            const float* __restrict__ mem, u16* __restrict__ mtb) {
    const int bx = blockIdx.x;
    if (bx >= 2048) {   // memory transpose+cast (256 blocks of 32x32 tiles)
        __shared__ float tile[32][33];
        const int j  = bx - 2048;
        const int c0 = (j & 15) * 32, r0 = (j >> 4) * 32;
        const int tr = threadIdx.x >> 3, tc = (threadIdx.x & 7) * 4;
        float4 v = *(const float4*)(mem + (size_t)(r0 + tr) * D_KV + c0 + tc);
        tile[tr][tc+0]=v.x; tile[tr][tc+1]=v.y; tile[tr][tc+2]=v.z; tile[tr][tc+3]=v.w;
        __syncthreads();
        ushort4 o;
        o.x = f32_to_bf16(tile[tc+0][tr]);
        o.y = f32_to_bf16(tile[tc+1][tr]);
        o.z = f32_to_bf16(tile[tc+2][tr]);
        o.w = f32_to_bf16(tile[tc+3][tr]);
        *(ushort4*)(mtb + (size_t)(c0 + tr) * D_KV + r0 + tc) = o;
        return;
    }
    const float* in; u16* out; int n4, blk, nblk;
    if (bx < 1024)      { in = x;  out = xb; n4 = BS*D_MODEL/4;      blk = bx;        nblk = 1024; }
    else if (bx < 1536) { in = Wq; out = wq; n4 = D_MODEL*D_MODEL/4; blk = bx - 1024; nblk = 512;  }
    else if (bx < 1792) { in = Wk; out = wk; n4 = D_KV*D_MODEL/4;    blk = bx - 1536; nblk = 256;  }
    else                { in = Wv; out = wv; n4 = D_KV*D_MODEL/4;    blk = bx - 1792; nblk = 256;  }
    for (int i = blk*256 + threadIdx.x; i < n4; i += nblk*256) {
        float4 v = ((const float4*)in)[i];
        ushort4 o;
        o.x = f32_to_bf16(v.x); o.y = f32_to_bf16(v.y);
        o.z = f32_to_bf16(v.z); o.w = f32_to_bf16(v.w);
        ((ushort4*)out)[i] = o;
    }
}

// ---------------------------------------------------------------------------
// Fused QKV projection: A[4096,2048] @ Wf[3072,2048]^T. Epilogue routes:
// n0 <  2048        -> Cq [4096,2048] row-major bf16
// 2048 <= n0 < 2560 -> Ck [4096,512]  row-major bf16
// n0 >= 2560 (V)    -> Vt [b][col][2048] TRANSPOSED bf16
// ---------------------------------------------------------------------------
__global__ __launch_bounds__(256) void gemm_qkv(const u16* __restrict__ A,
                                                const u16* __restrict__ Wf,
                                                u16* __restrict__ Cq,
                                                u16* __restrict__ Ck,
                                                u16* __restrict__ Vt) {
    __shared__ __align__(16) u16 As[128*32];
    __shared__ __align__(16) u16 Bs[128*32];
    const int K = D_MODEL;
    const int tid  = threadIdx.x;
    const int lane = tid & 63;
    const int wid  = tid >> 6;
    const int m0 = blockIdx.y * 128, n0 = blockIdx.x * 128;
    const int wr = (wid >> 1) * 64, wc = (wid & 1) * 64;
    const int lq = lane & 15, lg = lane >> 4;
    const int srow = tid >> 2;
    const int scol = (tid & 3) * 8;
    f32x4 acc[4][4] = {};
    const u16* Ag = A  + (size_t)(m0 + srow) * K + scol;
    const u16* Wg = Wf + (size_t)(n0 + srow) * K + scol;
    for (int k0 = 0; k0 < K; k0 += 32) {
        __syncthreads();
        load_lds16(Ag + k0,                 &As[srow*32 + scol]);
        load_lds16(Ag + k0 + (size_t)64*K,  &As[(srow+64)*32 + scol]);
        load_lds16(Wg + k0,                 &Bs[srow*32 + scol]);
        load_lds16(Wg + k0 + (size_t)64*K,  &Bs[(srow+64)*32 + scol]);
        __syncthreads();
        bf16x8 a[4], b[4];
        #pragma unroll
        for (int mi = 0; mi < 4; ++mi)
            a[mi] = *(const bf16x8*)&As[(wr + mi*16 + lq)*32 + lg*8];
        #pragma unroll
        for (int ni = 0; ni < 4; ++ni)
            b[ni] = *(const bf16x8*)&Bs[(wc + ni*16 + lq)*32 + lg*8];
        #pragma unroll
        for (int mi = 0; mi < 4; ++mi)
            #pragma unroll
            for (int ni = 0; ni < 4; ++ni)
                acc[mi][ni] = mfma16(a[mi], b[ni], acc[mi][ni]);
    }
    if (n0 < D_MODEL) {
        #pragma unroll
        for (int mi = 0; mi < 4; ++mi)
            #pragma unroll
            for (int ni = 0; ni < 4; ++ni)
                #pragma unroll
                for (int r = 0; r < 4; ++r)
                    Cq[(size_t)(m0 + wr + mi*16 + lg*4 + r) * D_MODEL + n0 + wc + ni*16 + lq] =
                        f32_to_bf16(acc[mi][ni][r]);
    } else if (n0 < D_MODEL + D_KV) {
        const int col = n0 - D_MODEL;
        #pragma unroll
        for (int mi = 0; mi < 4; ++mi)
            #pragma unroll
            for (int ni = 0; ni < 4; ++ni)
                #pragma unroll
                for (int r = 0; r < 4; ++r)
                    Ck[(size_t)(m0 + wr + mi*16 + lg*4 + r) * D_KV + col + wc + ni*16 + lq] =
                        f32_to_bf16(acc[mi][ni][r]);
    } else {
        const int cbase = n0 - (D_MODEL + D_KV);
        #pragma unroll
        for (int mi = 0; mi < 4; ++mi) {
            int row = m0 + wr + mi*16 + lg*4;     // 4 consecutive seq rows
            int bb  = row >> 11;
            int seq = row & (SEQ - 1);
            #pragma unroll
            for (int ni = 0; ni < 4; ++ni) {
                int col = cbase + wc + ni*16 + lq;
                union { u16 h[4]; uint2 d; } t;
                #pragma unroll
                for (int r = 0; r < 4; ++r) t.h[r] = f32_to_bf16(acc[mi][ni][r]);
                *(uint2*)(Vt + ((size_t)(bb * D_KV + col)) * SEQ + seq) = t.d;
            }
        }
    }
}

// ---------------------------------------------------------------------------
// Flash attention v8: v6 inner loop + K-split across blocks. Block (qtile,
// bh, g) handles keys [g*1024, g*1024+1024). Unnormalized O and lsum are
// combined via f32 atomic adds (exactly 2 adds/element -> bitwise
// deterministic by commutativity). Normalization folded into mem_gemm.
// 1024 blocks -> 4 blocks/CU -> 4 waves/SIMD (vs 2 before).
// ---------------------------------------------------------------------------
#define PACK_P(sc0, sc1, pf)  do {                                          \
    u32 Wp[8][2];                                                           \
    _Pragma("unroll")                                                       \
    for (int q = 0; q < 4; ++q) {                                           \
        Wp[q][0]   = cvt_pk_bf16(sc0[4*q],   sc0[4*q+1]);                   \
        Wp[q][1]   = cvt_pk_bf16(sc0[4*q+2], sc0[4*q+3]);                   \
        Wp[4+q][0] = cvt_pk_bf16(sc1[4*q],   sc1[4*q+1]);                   \
        Wp[4+q][1] = cvt_pk_bf16(sc1[4*q+2], sc1[4*q+3]);                   \
    }                                                                       \
    _Pragma("unroll")                                                       \
    for (int s = 0; s < 4; ++s) {                                           \
        const int b0 = (s >> 1)*4 + 2*(s & 1);                              \
        u32 a0 = Wp[b0][0], c0 = Wp[b0+1][0];                               \
        u32 a1 = Wp[b0][1], c1 = Wp[b0+1][1];                               \
        asm("v_permlane32_swap_b32 %0, %1" : "+v"(a0), "+v"(c0));           \
        asm("v_permlane32_swap_b32 %0, %1" : "+v"(a1), "+v"(c1));           \
        pf[s].w[0] = a0; pf[s].w[1] = a1;                                   \
        pf[s].w[2] = c0; pf[s].w[3] = c1;                                   \
    }                                                                       \
} while (0)

__global__ __launch_bounds__(256, 4) void attn_mfma(const u16* __restrict__ qb,
                                                    const u16* __restrict__ kb,
                                                    const u16* __restrict__ vtb,
                                                    float* __restrict__ out,
                                                    float* __restrict__ lsumb) {
    __shared__ __align__(16) u16 Ks [2][4096];   // [64 key][64 dim], XOR-swizzled
    __shared__ __align__(16) u16 VTs[2][4096];   // [64 dim][64 key], XOR-swizzled
    const int tid = threadIdx.x, lane = tid & 63, wid = tid >> 6;
    const int lq = lane & 31, hl = lane >> 5;
    // XCD swizzle: 1024 blocks = 8 XCDs x 128; (g,qtile) fastest in a chunk
    const int swz   = (blockIdx.x & 7) * 128 + (blockIdx.x >> 3);
    const int g     = swz & 1;                    // key half
    const int qtile = (swz >> 1) & 31;
    const int bh    = swz >> 6;
    const int b = bh >> 3, h = bh & 7;
    const int s0 = qtile * 64;
    const int qcol = wid * D_KV + h * D_HEAD;     // nq = wid
    const size_t rowbase = (size_t)b * SEQ;

    // Q B-frags, two 32-row groups, pre-scaled by 0.125*log2(e)
    bf16x8 qA[4], qB[4];
    {
        const float C = 0.18033688011112042f;
        const u16* qsA = qb + (rowbase + s0 + lq)      * D_MODEL + qcol + 8*hl;
        const u16* qsB = qb + (rowbase + s0 + 32 + lq) * D_MODEL + qcol + 8*hl;
        #pragma unroll
        for (int s = 0; s < 4; ++s) {
            bf16x8 ta = *(const bf16x8*)(qsA + 16*s);
            bf16x8 tb = *(const bf16x8*)(qsB + 16*s);
            #pragma unroll
            for (int e = 0; e < 8; ++e) {
                ta[e] = (short)f32_to_bf16(bf16_to_f32((u16)ta[e]) * C);
                tb[e] = (short)f32_to_bf16(bf16_to_f32((u16)tb[e]) * C);
            }
            qA[s] = ta; qB[s] = tb;
        }
    }

    // staging source offsets (pre-swizzled so LDS dest stays linear)
    const char* kbase = (const char*)(kb + rowbase * D_KV + h * D_HEAD)
                        + (size_t)g * 1024 * (D_KV*2);
    const char* vbase = (const char*)(vtb + ((size_t)b * D_KV + h * D_HEAD) * SEQ)
                        + (size_t)g * 1024 * 2;
    int ksrc_off[2], vsrc_off[2];
    #pragma unroll
    for (int c = 0; c < 2; ++c) {
        int o   = c*4096 + tid*16;
        int row = o >> 7;
        int col = (o & 127) ^ ((row & 7) << 4);
        ksrc_off[c] = row*(D_KV*2) + col;       // K row stride 1024 B
        vsrc_off[c] = row*(SEQ*2) + col;        // VT row stride 4096 B
    }

    f32x16 o0A = {}, o1A = {}, o0B = {}, o1B = {}, laccA = {}, laccB = {};
    Frag ones;
    #pragma unroll
    for (int i = 0; i < 4; ++i) ones.w[i] = 0x3F803F80u;   // bf16 1.0 pairs

    const int NT = 1024 / 64;                   // 16 tiles in this key half
    #pragma unroll
    for (int c = 0; c < 2; ++c) {               // prologue: tile 0 -> buf 0
        load_lds16(kbase + ksrc_off[c], (char*)Ks[0]  + c*4096 + tid*16);
        load_lds16(vbase + vsrc_off[c], (char*)VTs[0] + c*4096 + tid*16);
    }

    const int swl = (lq & 7) << 4;
    for (int j = 0; j < NT; ++j) {
        const int buf = j & 1;
        __syncthreads();                        // drains staged loads + joins
        if (j + 1 < NT) {
            const char* kj = kbase + (size_t)(j+1)*64*(D_KV*2);
            const char* vj = vbase + (size_t)(j+1)*128;
            #pragma unroll
            for (int c = 0; c < 2; ++c) {
                load_lds16(kj + ksrc_off[c], (char*)Ks[buf^1]  + c*4096 + tid*16);
                load_lds16(vj + vsrc_off[c], (char*)VTs[buf^1] + c*4096 + tid*16);
            }
        }

        // ---- QK^T: each K-frag read feeds both q-groups ----
        f32x16 sA0 = {}, sA1 = {}, sB0 = {}, sB1 = {};
        const char* Kc = (const char*)Ks[buf];
        __builtin_amdgcn_s_setprio(1);
        #pragma unroll
        for (int s = 0; s < 4; ++s) {
            int col = 32*s + 16*hl;
            bf16x8 k0 = *(const bf16x8*)(Kc + (( lq      *128 + col) ^ swl));
            bf16x8 k1 = *(const bf16x8*)(Kc + (((lq + 32)*128 + col) ^ swl));
            sA0 = mfma32(k0, qA[s], sA0);
            sB0 = mfma32(k0, qB[s], sB0);
            sA1 = mfma32(k1, qA[s], sA1);
            sB1 = mfma32(k1, qB[s], sB1);
        }
        __builtin_amdgcn_s_setprio(0);

        // ---- P = 2^sc (no max; range-safe, r8-verified numerics) ----
        #pragma unroll
        for (int i = 0; i < 16; ++i) sA0[i] = exp2_fast(sA0[i]);
        #pragma unroll
        for (int i = 0; i < 16; ++i) sA1[i] = exp2_fast(sA1[i]);
        #pragma unroll
        for (int i = 0; i < 16; ++i) sB0[i] = exp2_fast(sB0[i]);
        #pragma unroll
        for (int i = 0; i < 16; ++i) sB1[i] = exp2_fast(sB1[i]);

        Frag pfA[4], pfB[4];
        PACK_P(sA0, sA1, pfA);
        PACK_P(sB0, sB1, pfB);

        // ---- PV + lsum: each V-frag read feeds both q-groups ----
        const char* Vc = (const char*)VTs[buf];
        __builtin_amdgcn_s_setprio(1);
        #pragma unroll
        for (int s = 0; s < 4; ++s) {
            int col = 32*s + 16*hl;
            bf16x8 v0 = *(const bf16x8*)(Vc + (( lq      *128 + col) ^ swl));
            bf16x8 v1 = *(const bf16x8*)(Vc + (((lq + 32)*128 + col) ^ swl));
            o0A   = mfma32(v0, pfA[s].v, o0A);
            o0B   = mfma32(v0, pfB[s].v, o0B);
            o1A   = mfma32(v1, pfA[s].v, o1A);
            o1B   = mfma32(v1, pfB[s].v, o1B);
            laccA = mfma32(ones.v, pfA[s].v, laccA);
            laccB = mfma32(ones.v, pfB[s].v, laccB);
        }
        __builtin_amdgcn_s_setprio(0);
    }

    // ---- epilogue: atomic-add unnormalized partials (2 adds/element) ----
    float* dstA = out + (rowbase + s0 + lq)      * D_MODEL + qcol;
    float* dstB = out + (rowbase + s0 + 32 + lq) * D_MODEL + qcol;
    #pragma unroll
    for (int q = 0; q < 4; ++q) {
        int dbase = 8*q + 4*hl;
        #pragma unroll
        for (int r = 0; r < 4; ++r) {
            unsafeAtomicAdd(dstA + dbase + r,      o0A[4*q + r]);
            unsafeAtomicAdd(dstA + 32 + dbase + r, o1A[4*q + r]);
            unsafeAtomicAdd(dstB + dbase + r,      o0B[4*q + r]);
            unsafeAtomicAdd(dstB + 32 + dbase + r, o1B[4*q + r]);
        }
    }
    if (hl == 0) {
        int rowA = (int)(rowbase + s0 + lq);
        unsafeAtomicAdd(lsumb + ((size_t)rowA       * 4 + wid) * 8 + h, laccA[0]);
        unsafeAtomicAdd(lsumb + ((size_t)(rowA + 32) * 4 + wid) * 8 + h, laccB[0]);
    }
}

// ---------------------------------------------------------------------------
// out[i][j] = out[i][j] * (1-w)/lsum[i,h] + w * (elu(q) @ memT^T)[i][j] /
// den[i]. den fused during staging; lsum normalization folded in (out holds
// unnormalized attention partial sums on entry).
// ---------------------------------------------------------------------------
__global__ __launch_bounds__(256) void mem_gemm_mfma(const u16* __restrict__ qbuf,
                                                     const u16* __restrict__ MT,
                                                     const float* __restrict__ mn,
                                                     float* __restrict__ out,
                                                     const float* __restrict__ lsumb,
                                                     const float* __restrict__ mw) {
    __shared__ __align__(16) u16 As[128*32];
    __shared__ __align__(16) u16 Bs[128*32];
    __shared__ float den_s[128];
    const int tid  = threadIdx.x;
    const int lane = tid & 63;
    const int wid  = tid >> 6;
    const int i0 = blockIdx.y * 128, n0 = blockIdx.x * 128;
    const int wr = (wid >> 1) * 64, wc = (wid & 1) * 64;
    const int lq = lane & 15, lg = lane >> 4;
    const int srow = tid >> 2;
    const int scol = (tid & 3) * 8;
    f32x4 acc[4][4] = {};
    float dpart0 = 0.f, dpart1 = 0.f;
    const u16* Bg = MT + (size_t)(n0 + srow) * D_KV + scol;
    for (int k0 = 0; k0 < D_KV; k0 += 32) {
        __syncthreads();
        float4 mn0 = *(const float4*)(mn + k0 + scol);
        float4 mn1 = *(const float4*)(mn + k0 + scol + 4);
        float mnr[8] = {mn0.x, mn0.y, mn0.z, mn0.w, mn1.x, mn1.y, mn1.z, mn1.w};
        #pragma unroll
        for (int half = 0; half < 2; ++half) {
            int row = half*64 + srow;
            bf16x8 v = *(const bf16x8*)(qbuf + (size_t)(i0 + row) * D_KV + k0 + scol);
            bf16x8 ov;
            float dp = 0.f;
            #pragma unroll
            for (int e = 0; e < 8; ++e) {
                float xv = bf16_to_f32((u16)v[e]);
                float el = xv > 0.f ? xv : __expf(xv) - 1.f;
                dp += el * mnr[e];
                ov[e] = (short)f32_to_bf16(el);
            }
            if (half) dpart1 += dp; else dpart0 += dp;
            *(bf16x8*)&As[row*32 + scol] = ov;
        }
        load_lds16(Bg + k0,                     &Bs[srow*32 + scol]);
        load_lds16(Bg + k0 + (size_t)64*D_KV,   &Bs[(srow+64)*32 + scol]);
        __syncthreads();
        bf16x8 a[4], b[4];
        #pragma unroll
        for (int mi = 0; mi < 4; ++mi)
            a[mi] = *(const bf16x8*)&As[(wr + mi*16 + lq)*32 + lg*8];
        #pragma unroll
        for (int ni = 0; ni < 4; ++ni)
            b[ni] = *(const bf16x8*)&Bs[(wc + ni*16 + lq)*32 + lg*8];
        #pragma unroll
        for (int mi = 0; mi < 4; ++mi)
            #pragma unroll
            for (int ni = 0; ni < 4; ++ni)
                acc[mi][ni] = mfma16(a[mi], b[ni], acc[mi][ni]);
    }
    // fold the 4 staging lanes (tid&3 = col quarters) of each row
    dpart0 += __shfl_xor(dpart0, 1);  dpart0 += __shfl_xor(dpart0, 2);
    dpart1 += __shfl_xor(dpart1, 1);  dpart1 += __shfl_xor(dpart1, 2);
    if ((tid & 3) == 0) { den_s[srow] = dpart0; den_s[srow + 64] = dpart1; }
    __syncthreads();
    const float w   = 1.f / (1.f + __expf(-mw[0]));
    const float omw = 1.f - w;
    const int hconst = (n0 + wc) >> 6;          // ni*16+lq < 64 -> wave-constant
    #pragma unroll
    for (int mi = 0; mi < 4; ++mi)
        #pragma unroll
        for (int r = 0; r < 4; ++r) {
            int rl  = wr + mi*16 + lg*4 + r;
            int row = i0 + rl;
            float gg  = w / den_s[rl];
            float inv = omw / lsumb[(size_t)row * 8 + hconst];
            #pragma unroll
            for (int ni = 0; ni < 4; ++ni) {
                float* dst = out + (size_t)row * D_KV + n0 + wc + ni*16 + lq;
                *dst = (*dst) * inv + acc[mi][ni][r] * gg;
            }
        }
}

// ---------------------------------------------------------------------------
extern "C" void kernel_launch(void* const* d_in, const int* in_sizes, int n_in,
                              void* d_out, int out_size, void* d_ws, size_t ws_size,
                              hipStream_t stream) {
    const float* x   = (const float*)d_in[0];
    const float* Wq  = (const float*)d_in[1];
    const float* Wk  = (const float*)d_in[2];
    const float* Wv  = (const float*)d_in[3];
    const float* mem = (const float*)d_in[4];
    const float* mn  = (const float*)d_in[5];
    const float* mw  = (const float*)d_in[6];
    float* out = (float*)d_out;

    u16*   qb    = (u16*)d_ws;                             // [4096,2048] bf16
    u16*   kb    = qb  + (size_t)BS * D_MODEL;             // [4096,512] K
    u16*   xb    = kb  + (size_t)BS * D_KV;                // [4096,2048]
    u16*   vtb   = xb  + (size_t)BS * D_MODEL;             // [2,512,2048] V^T
    u16*   mtb   = vtb + (size_t)BATCH * D_KV * SEQ;       // [512,512] memT
    float* lsumb = (float*)(mtb + (size_t)D_KV * D_KV);    // [16384,8] f32
    // Wq|Wk|Wv bf16 (12.6 MB) lives in d_out scratch; consumed by the qkv
    // gemm, then out is memset + rebuilt by attn/mem_gemm. Deterministic.
    u16* wf = (u16*)d_out;

    prep<<<2304, 256, 0, stream>>>(x, xb,
                                   Wq, wf,
                                   Wk, wf + (size_t)D_MODEL*D_MODEL,
                                   Wv, wf + (size_t)(D_MODEL+D_KV)*D_MODEL,
                                   mem, mtb);
    gemm_qkv<<<dim3(NQKV/128, BS/128), 256, 0, stream>>>(xb, wf, qb, kb, vtb);
    hipMemsetAsync(out, 0, (size_t)MROWS * D_KV * sizeof(float), stream);
    hipMemsetAsync(lsumb, 0, (size_t)MROWS * 8 * sizeof(float), stream);
    attn_mfma<<<dim3(SEQ/64 * BATCH*N_HEAD * 2), 256, 0, stream>>>(qb, kb, vtb, out, lsumb);
    mem_gemm_mfma<<<dim3(D_KV/128, MROWS/128), 256, 0, stream>>>(qb, mtb, mn, out, lsumb, mw);
}

// Round 13
// 188.482 us; speedup vs baseline: 6.3563x; 6.3563x over previous
//
#include <hip/hip_runtime.h>
#include <hip/hip_bf16.h>
#include <math.h>

#define D_MODEL 2048
#define N_QUERY 4
#define N_HEAD  8
#define D_HEAD  64
#define D_KV    512
#define BATCH   2
#define SEQ     2048
#define BS      (BATCH*SEQ)      /* 4096 */
#define MROWS   (BS*N_QUERY)     /* 16384 */
#define NQKV    3072             /* fused Q|K|V gemm width */

typedef __attribute__((ext_vector_type(8)))  short bf16x8;
typedef __attribute__((ext_vector_type(4)))  float f32x4;
typedef __attribute__((ext_vector_type(16))) float f32x16;
typedef unsigned short u16;
typedef unsigned int   u32;

union Frag { bf16x8 v; u32 w[4]; };

__device__ __forceinline__ f32x4 mfma16(bf16x8 a, bf16x8 b, f32x4 c) {
    return __builtin_amdgcn_mfma_f32_16x16x32_bf16(a, b, c, 0, 0, 0);
}
__device__ __forceinline__ f32x16 mfma32(bf16x8 a, bf16x8 b, f32x16 c) {
    return __builtin_amdgcn_mfma_f32_32x32x16_bf16(a, b, c, 0, 0, 0);
}
__device__ __forceinline__ u16 f32_to_bf16(float f) {
    u32 u = __float_as_uint(f);
    u32 r = (u + 0x7fffu + ((u >> 16) & 1u)) >> 16;   // RTNE
    return (u16)r;
}
__device__ __forceinline__ float bf16_to_f32(u16 h) {
    return __uint_as_float(((u32)h) << 16);
}
__device__ __forceinline__ u32 cvt_pk_bf16(float lo, float hi) {
    u32 r;
    asm volatile("v_cvt_pk_bf16_f32 %0, %1, %2" : "=v"(r) : "v"(lo), "v"(hi));
    return r;
}
// exp2 via BUILTIN: compiler must see the TRANS op for hazard waits (r8 lesson)
__device__ __forceinline__ float exp2_fast(float x) {
#if __has_builtin(__builtin_amdgcn_exp2f)
    return __builtin_amdgcn_exp2f(x);
#else
    return exp2f(x);
#endif
}
__device__ __forceinline__ void load_lds16(const void* g, void* l) {
    using GP = const __attribute__((address_space(1))) unsigned char*;
    using LP = __attribute__((address_space(3))) unsigned char*;
    __builtin_amdgcn_global_load_lds(
        reinterpret_cast<GP>(reinterpret_cast<uintptr_t>(g)),
        reinterpret_cast<LP>(reinterpret_cast<uintptr_t>(l)), 16, 0, 0);
}

// ---------------------------------------------------------------------------
// prep: blocks [0,1024) x-cast, [1024,1536) Wq, [1536,1792) Wk, [1792,2048)
// Wv, [2048,2304) memory f32 -> memT bf16 transposed.
// ---------------------------------------------------------------------------
__global__ __launch_bounds__(256) void prep(const float* __restrict__ x,   u16* __restrict__ xb,
                                            const float* __restrict__ Wq,  u16* __restrict__ wq,
                                            const float* __restrict__ Wk,  u16* __restrict__ wk,
                                            const float* __restrict__ Wv,  u16* __restrict__ wv,
                                            const float* __restrict__ mem, u16* __restrict__ mtb) {
    const int bx = blockIdx.x;
    if (bx >= 2048) {   // memory transpose+cast (256 blocks of 32x32 tiles)
        __shared__ float tile[32][33];
        const int j  = bx - 2048;
        const int c0 = (j & 15) * 32, r0 = (j >> 4) * 32;
        const int tr = threadIdx.x >> 3, tc = (threadIdx.x & 7) * 4;
        float4 v = *(const float4*)(mem + (size_t)(r0 + tr) * D_KV + c0 + tc);
        tile[tr][tc+0]=v.x; tile[tr][tc+1]=v.y; tile[tr][tc+2]=v.z; tile[tr][tc+3]=v.w;
        __syncthreads();
        ushort4 o;
        o.x = f32_to_bf16(tile[tc+0][tr]);
        o.y = f32_to_bf16(tile[tc+1][tr]);
        o.z = f32_to_bf16(tile[tc+2][tr]);
        o.w = f32_to_bf16(tile[tc+3][tr]);
        *(ushort4*)(mtb + (size_t)(c0 + tr) * D_KV + r0 + tc) = o;
        return;
    }
    const float* in; u16* out; int n4, blk, nblk;
    if (bx < 1024)      { in = x;  out = xb; n4 = BS*D_MODEL/4;      blk = bx;        nblk = 1024; }
    else if (bx < 1536) { in = Wq; out = wq; n4 = D_MODEL*D_MODEL/4; blk = bx - 1024; nblk = 512;  }
    else if (bx < 1792) { in = Wk; out = wk; n4 = D_KV*D_MODEL/4;    blk = bx - 1536; nblk = 256;  }
    else                { in = Wv; out = wv; n4 = D_KV*D_MODEL/4;    blk = bx - 1792; nblk = 256;  }
    for (int i = blk*256 + threadIdx.x; i < n4; i += nblk*256) {
        float4 v = ((const float4*)in)[i];
        ushort4 o;
        o.x = f32_to_bf16(v.x); o.y = f32_to_bf16(v.y);
        o.z = f32_to_bf16(v.z); o.w = f32_to_bf16(v.w);
        ((ushort4*)out)[i] = o;
    }
}

// ---------------------------------------------------------------------------
// Fused QKV projection: A[4096,2048] @ Wf[3072,2048]^T. Epilogue routes:
// n0 <  2048        -> Cq [4096,2048] row-major bf16
// 2048 <= n0 < 2560 -> Ck [4096,512]  row-major bf16
// n0 >= 2560 (V)    -> Vt [b][col][2048] TRANSPOSED bf16
// ---------------------------------------------------------------------------
__global__ __launch_bounds__(256) void gemm_qkv(const u16* __restrict__ A,
                                                const u16* __restrict__ Wf,
                                                u16* __restrict__ Cq,
                                                u16* __restrict__ Ck,
                                                u16* __restrict__ Vt) {
    __shared__ __align__(16) u16 As[128*32];
    __shared__ __align__(16) u16 Bs[128*32];
    const int K = D_MODEL;
    const int tid  = threadIdx.x;
    const int lane = tid & 63;
    const int wid  = tid >> 6;
    const int m0 = blockIdx.y * 128, n0 = blockIdx.x * 128;
    const int wr = (wid >> 1) * 64, wc = (wid & 1) * 64;
    const int lq = lane & 15, lg = lane >> 4;
    const int srow = tid >> 2;
    const int scol = (tid & 3) * 8;
    f32x4 acc[4][4] = {};
    const u16* Ag = A  + (size_t)(m0 + srow) * K + scol;
    const u16* Wg = Wf + (size_t)(n0 + srow) * K + scol;
    for (int k0 = 0; k0 < K; k0 += 32) {
        __syncthreads();
        load_lds16(Ag + k0,                 &As[srow*32 + scol]);
        load_lds16(Ag + k0 + (size_t)64*K,  &As[(srow+64)*32 + scol]);
        load_lds16(Wg + k0,                 &Bs[srow*32 + scol]);
        load_lds16(Wg + k0 + (size_t)64*K,  &Bs[(srow+64)*32 + scol]);
        __syncthreads();
        bf16x8 a[4], b[4];
        #pragma unroll
        for (int mi = 0; mi < 4; ++mi)
            a[mi] = *(const bf16x8*)&As[(wr + mi*16 + lq)*32 + lg*8];
        #pragma unroll
        for (int ni = 0; ni < 4; ++ni)
            b[ni] = *(const bf16x8*)&Bs[(wc + ni*16 + lq)*32 + lg*8];
        #pragma unroll
        for (int mi = 0; mi < 4; ++mi)
            #pragma unroll
            for (int ni = 0; ni < 4; ++ni)
                acc[mi][ni] = mfma16(a[mi], b[ni], acc[mi][ni]);
    }
    if (n0 < D_MODEL) {
        #pragma unroll
        for (int mi = 0; mi < 4; ++mi)
            #pragma unroll
            for (int ni = 0; ni < 4; ++ni)
                #pragma unroll
                for (int r = 0; r < 4; ++r)
                    Cq[(size_t)(m0 + wr + mi*16 + lg*4 + r) * D_MODEL + n0 + wc + ni*16 + lq] =
                        f32_to_bf16(acc[mi][ni][r]);
    } else if (n0 < D_MODEL + D_KV) {
        const int col = n0 - D_MODEL;
        #pragma unroll
        for (int mi = 0; mi < 4; ++mi)
            #pragma unroll
            for (int ni = 0; ni < 4; ++ni)
                #pragma unroll
                for (int r = 0; r < 4; ++r)
                    Ck[(size_t)(m0 + wr + mi*16 + lg*4 + r) * D_KV + col + wc + ni*16 + lq] =
                        f32_to_bf16(acc[mi][ni][r]);
    } else {
        const int cbase = n0 - (D_MODEL + D_KV);
        #pragma unroll
        for (int mi = 0; mi < 4; ++mi) {
            int row = m0 + wr + mi*16 + lg*4;     // 4 consecutive seq rows
            int bb  = row >> 11;
            int seq = row & (SEQ - 1);
            #pragma unroll
            for (int ni = 0; ni < 4; ++ni) {
                int col = cbase + wc + ni*16 + lq;
                union { u16 h[4]; uint2 d; } t;
                #pragma unroll
                for (int r = 0; r < 4; ++r) t.h[r] = f32_to_bf16(acc[mi][ni][r]);
                *(uint2*)(Vt + ((size_t)(bb * D_KV + col)) * SEQ + seq) = t.d;
            }
        }
    }
}

// ---------------------------------------------------------------------------
// Flash attention v9: v6 inner loop (r11-exact math) + triple-buffered K/V
// staging with COUNTED vmcnt before a raw s_barrier (T4): each wave waits
// vmcnt(4) (own tile-j loads landed; tile-j+1 in flight), then s_barrier
// propagates the guarantee across waves. Prefetch issued AFTER compute gets
// a full iteration of latency cover; no vmcnt(0) drain in the main loop.
// ---------------------------------------------------------------------------
#define PACK_P(sc0, sc1, pf)  do {                                          \
    u32 Wp[8][2];                                                           \
    _Pragma("unroll")                                                       \
    for (int q = 0; q < 4; ++q) {                                           \
        Wp[q][0]   = cvt_pk_bf16(sc0[4*q],   sc0[4*q+1]);                   \
        Wp[q][1]   = cvt_pk_bf16(sc0[4*q+2], sc0[4*q+3]);                   \
        Wp[4+q][0] = cvt_pk_bf16(sc1[4*q],   sc1[4*q+1]);                   \
        Wp[4+q][1] = cvt_pk_bf16(sc1[4*q+2], sc1[4*q+3]);                   \
    }                                                                       \
    _Pragma("unroll")                                                       \
    for (int s = 0; s < 4; ++s) {                                           \
        const int b0 = (s >> 1)*4 + 2*(s & 1);                              \
        u32 a0 = Wp[b0][0], c0 = Wp[b0+1][0];                               \
        u32 a1 = Wp[b0][1], c1 = Wp[b0+1][1];                               \
        asm("v_permlane32_swap_b32 %0, %1" : "+v"(a0), "+v"(c0));           \
        asm("v_permlane32_swap_b32 %0, %1" : "+v"(a1), "+v"(c1));           \
        pf[s].w[0] = a0; pf[s].w[1] = a1;                                   \
        pf[s].w[2] = c0; pf[s].w[3] = c1;                                   \
    }                                                                       \
} while (0)

__global__ __launch_bounds__(256, 2) void attn_mfma(const u16* __restrict__ qb,
                                                    const u16* __restrict__ kb,
                                                    const u16* __restrict__ vtb,
                                                    float* __restrict__ out,
                                                    const float* __restrict__ mw) {
    __shared__ __align__(16) u16 Ks [3][4096];   // [64 key][64 dim], XOR-swizzled
    __shared__ __align__(16) u16 VTs[3][4096];   // [64 dim][64 key], XOR-swizzled
    const int tid = threadIdx.x, lane = tid & 63, wid = tid >> 6;
    const int lq = lane & 31, hl = lane >> 5;
    // XCD swizzle: 512 blocks = 8 XCDs x 64; qtile fastest within a chunk
    const int swz   = (blockIdx.x & 7) * 64 + (blockIdx.x >> 3);
    const int qtile = swz & 31;
    const int bh    = swz >> 5;
    const int b = bh >> 3, h = bh & 7;
    const int s0 = qtile * 64;
    const int qcol = wid * D_KV + h * D_HEAD;     // nq = wid
    const size_t rowbase = (size_t)b * SEQ;

    // Q B-frags, two 32-row groups, pre-scaled by 0.125*log2(e)
    bf16x8 qA[4], qB[4];
    {
        const float C = 0.18033688011112042f;
        const u16* qsA = qb + (rowbase + s0 + lq)      * D_MODEL + qcol + 8*hl;
        const u16* qsB = qb + (rowbase + s0 + 32 + lq) * D_MODEL + qcol + 8*hl;
        #pragma unroll
        for (int s = 0; s < 4; ++s) {
            bf16x8 ta = *(const bf16x8*)(qsA + 16*s);
            bf16x8 tb = *(const bf16x8*)(qsB + 16*s);
            #pragma unroll
            for (int e = 0; e < 8; ++e) {
                ta[e] = (short)f32_to_bf16(bf16_to_f32((u16)ta[e]) * C);
                tb[e] = (short)f32_to_bf16(bf16_to_f32((u16)tb[e]) * C);
            }
            qA[s] = ta; qB[s] = tb;
        }
    }

    // staging source offsets (pre-swizzled so LDS dest stays linear)
    const char* kbase = (const char*)(kb + rowbase * D_KV + h * D_HEAD);
    const char* vbase = (const char*)(vtb + ((size_t)b * D_KV + h * D_HEAD) * SEQ);
    int ksrc_off[2], vsrc_off[2];
    #pragma unroll
    for (int c = 0; c < 2; ++c) {
        int o   = c*4096 + tid*16;
        int row = o >> 7;
        int col = (o & 127) ^ ((row & 7) << 4);
        ksrc_off[c] = row*(D_KV*2) + col;       // K row stride 1024 B
        vsrc_off[c] = row*(SEQ*2) + col;        // VT row stride 4096 B
    }

    f32x16 o0A = {}, o1A = {}, o0B = {}, o1B = {}, laccA = {}, laccB = {};
    Frag ones;
    #pragma unroll
    for (int i = 0; i < 4; ++i) ones.w[i] = 0x3F803F80u;   // bf16 1.0 pairs

    const int NT = SEQ / 64;
    // prologue: tiles 0,1 -> bufs 0,1 (4 wave-vm-ops per tile per wave)
    #pragma unroll
    for (int t = 0; t < 2; ++t) {
        const char* kj = kbase + (size_t)t*64*(D_KV*2);
        const char* vj = vbase + (size_t)t*128;
        #pragma unroll
        for (int c = 0; c < 2; ++c) {
            load_lds16(kj + ksrc_off[c], (char*)Ks[t]  + c*4096 + tid*16);
            load_lds16(vj + vsrc_off[c], (char*)VTs[t] + c*4096 + tid*16);
        }
    }

    const int swl = (lq & 7) << 4;
    int buf = 0;
    #pragma unroll 1
    for (int j = 0; j < NT; ++j) {
        // counted wait: own tile-j loads landed (tile-j+1 may stay in flight);
        // barrier propagates the per-wave guarantee to the whole block.
        if (j == NT - 1) asm volatile("s_waitcnt vmcnt(0)" ::: "memory");
        else             asm volatile("s_waitcnt vmcnt(4)" ::: "memory");
        __builtin_amdgcn_s_barrier();
        __builtin_amdgcn_sched_barrier(0);

        // ---- QK^T: each K-frag read feeds both q-groups ----
        f32x16 sA0 = {}, sA1 = {}, sB0 = {}, sB1 = {};
        const char* Kc = (const char*)Ks[buf];
        __builtin_amdgcn_s_setprio(1);
        #pragma unroll
        for (int s = 0; s < 4; ++s) {
            int col = 32*s + 16*hl;
            bf16x8 k0 = *(const bf16x8*)(Kc + (( lq      *128 + col) ^ swl));
            bf16x8 k1 = *(const bf16x8*)(Kc + (((lq + 32)*128 + col) ^ swl));
            sA0 = mfma32(k0, qA[s], sA0);
            sB0 = mfma32(k0, qB[s], sB0);
            sA1 = mfma32(k1, qA[s], sA1);
            sB1 = mfma32(k1, qB[s], sB1);
        }
        __builtin_amdgcn_s_setprio(0);

        // ---- P = 2^sc (no max; range-safe, r8-verified numerics) ----
        #pragma unroll
        for (int i = 0; i < 16; ++i) sA0[i] = exp2_fast(sA0[i]);
        #pragma unroll
        for (int i = 0; i < 16; ++i) sA1[i] = exp2_fast(sA1[i]);
        #pragma unroll
        for (int i = 0; i < 16; ++i) sB0[i] = exp2_fast(sB0[i]);
        #pragma unroll
        for (int i = 0; i < 16; ++i) sB1[i] = exp2_fast(sB1[i]);

        Frag pfA[4], pfB[4];
        PACK_P(sA0, sA1, pfA);
        PACK_P(sB0, sB1, pfB);

        // ---- PV + lsum: each V-frag read feeds both q-groups ----
        const char* Vc = (const char*)VTs[buf];
        __builtin_amdgcn_s_setprio(1);
        #pragma unroll
        for (int s = 0; s < 4; ++s) {
            int col = 32*s + 16*hl;
            bf16x8 v0 = *(const bf16x8*)(Vc + (( lq      *128 + col) ^ swl));
            bf16x8 v1 = *(const bf16x8*)(Vc + (((lq + 32)*128 + col) ^ swl));
            o0A   = mfma32(v0, pfA[s].v, o0A);
            o0B   = mfma32(v0, pfB[s].v, o0B);
            o1A   = mfma32(v1, pfA[s].v, o1A);
            o1B   = mfma32(v1, pfB[s].v, o1B);
            laccA = mfma32(ones.v, pfA[s].v, laccA);
            laccB = mfma32(ones.v, pfB[s].v, laccB);
        }
        __builtin_amdgcn_s_setprio(0);

        // ---- prefetch tile j+2 into buf (j+2)%3 == the buffer read at j-1
        // (its readers are all behind this iteration's head barrier) ----
        if (j + 2 < NT) {
            int sb = buf + 2; if (sb >= 3) sb -= 3;
            const char* kj = kbase + (size_t)(j+2)*64*(D_KV*2);
            const char* vj = vbase + (size_t)(j+2)*128;
            #pragma unroll
            for (int c = 0; c < 2; ++c) {
                load_lds16(kj + ksrc_off[c], (char*)Ks[sb]  + c*4096 + tid*16);
                load_lds16(vj + vsrc_off[c], (char*)VTs[sb] + c*4096 + tid*16);
            }
        }
        buf = (buf == 2) ? 0 : buf + 1;
    }

    // ---- epilogue ----
    const float w = 1.f / (1.f + __expf(-mw[0]));
    const float invA = (1.f - w) / laccA[0];
    const float invB = (1.f - w) / laccB[0];
    float* dstA = out + (rowbase + s0 + lq)      * D_MODEL + qcol;
    float* dstB = out + (rowbase + s0 + 32 + lq) * D_MODEL + qcol;
    #pragma unroll
    for (int g = 0; g < 4; ++g) {
        int dbase = 8*g + 4*hl;
        *(float4*)(dstA + dbase) =
            make_float4(o0A[4*g]*invA, o0A[4*g+1]*invA, o0A[4*g+2]*invA, o0A[4*g+3]*invA);
        *(float4*)(dstA + 32 + dbase) =
            make_float4(o1A[4*g]*invA, o1A[4*g+1]*invA, o1A[4*g+2]*invA, o1A[4*g+3]*invA);
        *(float4*)(dstB + dbase) =
            make_float4(o0B[4*g]*invB, o0B[4*g+1]*invB, o0B[4*g+2]*invB, o0B[4*g+3]*invB);
        *(float4*)(dstB + 32 + dbase) =
            make_float4(o1B[4*g]*invB, o1B[4*g+1]*invB, o1B[4*g+2]*invB, o1B[4*g+3]*invB);
    }
}

// ---------------------------------------------------------------------------
// out[i][j] += w * (elu(q) @ memT^T)[i][j] / den[i], den fused during staging.
// ---------------------------------------------------------------------------
__global__ __launch_bounds__(256) void mem_gemm_mfma(const u16* __restrict__ qbuf,
                                                     const u16* __restrict__ MT,
                                                     const float* __restrict__ mn,
                                                     float* __restrict__ out,
                                                     const float* __restrict__ mw) {
    __shared__ __align__(16) u16 As[128*32];
    __shared__ __align__(16) u16 Bs[128*32];
    __shared__ float den_s[128];
    const int tid  = threadIdx.x;
    const int lane = tid & 63;
    const int wid  = tid >> 6;
    const int i0 = blockIdx.y * 128, n0 = blockIdx.x * 128;
    const int wr = (wid >> 1) * 64, wc = (wid & 1) * 64;
    const int lq = lane & 15, lg = lane >> 4;
    const int srow = tid >> 2;
    const int scol = (tid & 3) * 8;
    f32x4 acc[4][4] = {};
    float dpart0 = 0.f, dpart1 = 0.f;
    const u16* Bg = MT + (size_t)(n0 + srow) * D_KV + scol;
    for (int k0 = 0; k0 < D_KV; k0 += 32) {
        __syncthreads();
        float4 mn0 = *(const float4*)(mn + k0 + scol);
        float4 mn1 = *(const float4*)(mn + k0 + scol + 4);
        float mnr[8] = {mn0.x, mn0.y, mn0.z, mn0.w, mn1.x, mn1.y, mn1.z, mn1.w};
        #pragma unroll
        for (int half = 0; half < 2; ++half) {
            int row = half*64 + srow;
            bf16x8 v = *(const bf16x8*)(qbuf + (size_t)(i0 + row) * D_KV + k0 + scol);
            bf16x8 ov;
            float dp = 0.f;
            #pragma unroll
            for (int e = 0; e < 8; ++e) {
                float xv = bf16_to_f32((u16)v[e]);
                float el = xv > 0.f ? xv : __expf(xv) - 1.f;
                dp += el * mnr[e];
                ov[e] = (short)f32_to_bf16(el);
            }
            if (half) dpart1 += dp; else dpart0 += dp;
            *(bf16x8*)&As[row*32 + scol] = ov;
        }
        load_lds16(Bg + k0,                     &Bs[srow*32 + scol]);
        load_lds16(Bg + k0 + (size_t)64*D_KV,   &Bs[(srow+64)*32 + scol]);
        __syncthreads();
        bf16x8 a[4], b[4];
        #pragma unroll
        for (int mi = 0; mi < 4; ++mi)
            a[mi] = *(const bf16x8*)&As[(wr + mi*16 + lq)*32 + lg*8];
        #pragma unroll
        for (int ni = 0; ni < 4; ++ni)
            b[ni] = *(const bf16x8*)&Bs[(wc + ni*16 + lq)*32 + lg*8];
        #pragma unroll
        for (int mi = 0; mi < 4; ++mi)
            #pragma unroll
            for (int ni = 0; ni < 4; ++ni)
                acc[mi][ni] = mfma16(a[mi], b[ni], acc[mi][ni]);
    }
    // fold the 4 staging lanes (tid&3 = col quarters) of each row
    dpart0 += __shfl_xor(dpart0, 1);  dpart0 += __shfl_xor(dpart0, 2);
    dpart1 += __shfl_xor(dpart1, 1);  dpart1 += __shfl_xor(dpart1, 2);
    if ((tid & 3) == 0) { den_s[srow] = dpart0; den_s[srow + 64] = dpart1; }
    __syncthreads();
    const float w = 1.f / (1.f + __expf(-mw[0]));
    #pragma unroll
    for (int mi = 0; mi < 4; ++mi)
        #pragma unroll
        for (int r = 0; r < 4; ++r) {
            int rl  = wr + mi*16 + lg*4 + r;
            float g = w / den_s[rl];
            int row = i0 + rl;
            #pragma unroll
            for (int ni = 0; ni < 4; ++ni) {
                float* dst = out + (size_t)row * D_KV + n0 + wc + ni*16 + lq;
                *dst += acc[mi][ni][r] * g;
            }
        }
}

// ---------------------------------------------------------------------------
extern "C" void kernel_launch(void* const* d_in, const int* in_sizes, int n_in,
                              void* d_out, int out_size, void* d_ws, size_t ws_size,
                              hipStream_t stream) {
    const float* x   = (const float*)d_in[0];
    const float* Wq  = (const float*)d_in[1];
    const float* Wk  = (const float*)d_in[2];
    const float* Wv  = (const float*)d_in[3];
    const float* mem = (const float*)d_in[4];
    const float* mn  = (const float*)d_in[5];
    const float* mw  = (const float*)d_in[6];
    float* out = (float*)d_out;

    u16* qb  = (u16*)d_ws;                               // [4096,2048] bf16
    u16* kb  = qb  + (size_t)BS * D_MODEL;               // [4096,512] K
    u16* xb  = kb  + (size_t)BS * D_KV;                  // [4096,2048]
    u16* vtb = xb  + (size_t)BS * D_MODEL;               // [2,512,2048] V^T
    u16* mtb = vtb + (size_t)BATCH * D_KV * SEQ;         // [512,512] memT
    // Wq|Wk|Wv bf16 (12.6 MB) lives in d_out scratch; consumed by the qkv
    // gemm, then attn fully overwrites all of d_out. Deterministic.
    u16* wf  = (u16*)d_out;

    prep<<<2304, 256, 0, stream>>>(x, xb,
                                   Wq, wf,
                                   Wk, wf + (size_t)D_MODEL*D_MODEL,
                                   Wv, wf + (size_t)(D_MODEL+D_KV)*D_MODEL,
                                   mem, mtb);
    gemm_qkv<<<dim3(NQKV/128, BS/128), 256, 0, stream>>>(xb, wf, qb, kb, vtb);
    attn_mfma<<<dim3(SEQ/64 * BATCH*N_HEAD), 256, 0, stream>>>(qb, kb, vtb, out, mw);
    mem_gemm_mfma<<<dim3(D_KV/128, MROWS/128), 256, 0, stream>>>(qb, mtb, mn, out, mw);
}

// Round 14
// 185.581 us; speedup vs baseline: 6.4557x; 1.0156x over previous
//
#include <hip/hip_runtime.h>
#include <hip/hip_bf16.h>
#include <math.h>

#define D_MODEL 2048
#define N_QUERY 4
#define N_HEAD  8
#define D_HEAD  64
#define D_KV    512
#define BATCH   2
#define SEQ     2048
#define BS      (BATCH*SEQ)      /* 4096 */
#define MROWS   (BS*N_QUERY)     /* 16384 */
#define NQKV    3072             /* fused Q|K|V gemm width */

typedef __attribute__((ext_vector_type(8)))  short bf16x8;
typedef __attribute__((ext_vector_type(4)))  float f32x4;
typedef __attribute__((ext_vector_type(16))) float f32x16;
typedef unsigned short u16;
typedef unsigned int   u32;

union Frag { bf16x8 v; u32 w[4]; };

__device__ __forceinline__ f32x4 mfma16(bf16x8 a, bf16x8 b, f32x4 c) {
    return __builtin_amdgcn_mfma_f32_16x16x32_bf16(a, b, c, 0, 0, 0);
}
__device__ __forceinline__ f32x16 mfma32(bf16x8 a, bf16x8 b, f32x16 c) {
    return __builtin_amdgcn_mfma_f32_32x32x16_bf16(a, b, c, 0, 0, 0);
}
__device__ __forceinline__ u16 f32_to_bf16(float f) {
    u32 u = __float_as_uint(f);
    u32 r = (u + 0x7fffu + ((u >> 16) & 1u)) >> 16;   // RTNE
    return (u16)r;
}
__device__ __forceinline__ float bf16_to_f32(u16 h) {
    return __uint_as_float(((u32)h) << 16);
}
__device__ __forceinline__ u32 cvt_pk_bf16(float lo, float hi) {
    u32 r;
    asm volatile("v_cvt_pk_bf16_f32 %0, %1, %2" : "=v"(r) : "v"(lo), "v"(hi));
    return r;
}
// exp2 via BUILTIN: compiler must see the TRANS op for hazard waits (r8 lesson)
__device__ __forceinline__ float exp2_fast(float x) {
#if __has_builtin(__builtin_amdgcn_exp2f)
    return __builtin_amdgcn_exp2f(x);
#else
    return exp2f(x);
#endif
}
__device__ __forceinline__ void load_lds16(const void* g, void* l) {
    using GP = const __attribute__((address_space(1))) unsigned char*;
    using LP = __attribute__((address_space(3))) unsigned char*;
    __builtin_amdgcn_global_load_lds(
        reinterpret_cast<GP>(reinterpret_cast<uintptr_t>(g)),
        reinterpret_cast<LP>(reinterpret_cast<uintptr_t>(l)), 16, 0, 0);
}

// ---------------------------------------------------------------------------
// prep: blocks [0,1024) x-cast, [1024,1536) Wq, [1536,1792) Wk, [1792,2048)
// Wv, [2048,2304) memory f32 -> memT bf16 transposed.
// ---------------------------------------------------------------------------
__global__ __launch_bounds__(256) void prep(const float* __restrict__ x,   u16* __restrict__ xb,
                                            const float* __restrict__ Wq,  u16* __restrict__ wq,
                                            const float* __restrict__ Wk,  u16* __restrict__ wk,
                                            const float* __restrict__ Wv,  u16* __restrict__ wv,
                                            const float* __restrict__ mem, u16* __restrict__ mtb) {
    const int bx = blockIdx.x;
    if (bx >= 2048) {   // memory transpose+cast (256 blocks of 32x32 tiles)
        __shared__ float tile[32][33];
        const int j  = bx - 2048;
        const int c0 = (j & 15) * 32, r0 = (j >> 4) * 32;
        const int tr = threadIdx.x >> 3, tc = (threadIdx.x & 7) * 4;
        float4 v = *(const float4*)(mem + (size_t)(r0 + tr) * D_KV + c0 + tc);
        tile[tr][tc+0]=v.x; tile[tr][tc+1]=v.y; tile[tr][tc+2]=v.z; tile[tr][tc+3]=v.w;
        __syncthreads();
        ushort4 o;
        o.x = f32_to_bf16(tile[tc+0][tr]);
        o.y = f32_to_bf16(tile[tc+1][tr]);
        o.z = f32_to_bf16(tile[tc+2][tr]);
        o.w = f32_to_bf16(tile[tc+3][tr]);
        *(ushort4*)(mtb + (size_t)(c0 + tr) * D_KV + r0 + tc) = o;
        return;
    }
    const float* in; u16* out; int n4, blk, nblk;
    if (bx < 1024)      { in = x;  out = xb; n4 = BS*D_MODEL/4;      blk = bx;        nblk = 1024; }
    else if (bx < 1536) { in = Wq; out = wq; n4 = D_MODEL*D_MODEL/4; blk = bx - 1024; nblk = 512;  }
    else if (bx < 1792) { in = Wk; out = wk; n4 = D_KV*D_MODEL/4;    blk = bx - 1536; nblk = 256;  }
    else                { in = Wv; out = wv; n4 = D_KV*D_MODEL/4;    blk = bx - 1792; nblk = 256;  }
    for (int i = blk*256 + threadIdx.x; i < n4; i += nblk*256) {
        float4 v = ((const float4*)in)[i];
        ushort4 o;
        o.x = f32_to_bf16(v.x); o.y = f32_to_bf16(v.y);
        o.z = f32_to_bf16(v.z); o.w = f32_to_bf16(v.w);
        ((ushort4*)out)[i] = o;
    }
}

// ---------------------------------------------------------------------------
// Fused QKV projection: A[4096,2048] @ Wf[3072,2048]^T. Epilogue routes:
// n0 <  2048        -> Cq [4096,2048] row-major bf16
// 2048 <= n0 < 2560 -> Ck [4096,512]  row-major bf16
// n0 >= 2560 (V)    -> Vt [b][col][2048] TRANSPOSED bf16
// ---------------------------------------------------------------------------
__global__ __launch_bounds__(256) void gemm_qkv(const u16* __restrict__ A,
                                                const u16* __restrict__ Wf,
                                                u16* __restrict__ Cq,
                                                u16* __restrict__ Ck,
                                                u16* __restrict__ Vt) {
    __shared__ __align__(16) u16 As[128*32];
    __shared__ __align__(16) u16 Bs[128*32];
    const int K = D_MODEL;
    const int tid  = threadIdx.x;
    const int lane = tid & 63;
    const int wid  = tid >> 6;
    const int m0 = blockIdx.y * 128, n0 = blockIdx.x * 128;
    const int wr = (wid >> 1) * 64, wc = (wid & 1) * 64;
    const int lq = lane & 15, lg = lane >> 4;
    const int srow = tid >> 2;
    const int scol = (tid & 3) * 8;
    f32x4 acc[4][4] = {};
    const u16* Ag = A  + (size_t)(m0 + srow) * K + scol;
    const u16* Wg = Wf + (size_t)(n0 + srow) * K + scol;
    for (int k0 = 0; k0 < K; k0 += 32) {
        __syncthreads();
        load_lds16(Ag + k0,                 &As[srow*32 + scol]);
        load_lds16(Ag + k0 + (size_t)64*K,  &As[(srow+64)*32 + scol]);
        load_lds16(Wg + k0,                 &Bs[srow*32 + scol]);
        load_lds16(Wg + k0 + (size_t)64*K,  &Bs[(srow+64)*32 + scol]);
        __syncthreads();
        bf16x8 a[4], b[4];
        #pragma unroll
        for (int mi = 0; mi < 4; ++mi)
            a[mi] = *(const bf16x8*)&As[(wr + mi*16 + lq)*32 + lg*8];
        #pragma unroll
        for (int ni = 0; ni < 4; ++ni)
            b[ni] = *(const bf16x8*)&Bs[(wc + ni*16 + lq)*32 + lg*8];
        #pragma unroll
        for (int mi = 0; mi < 4; ++mi)
            #pragma unroll
            for (int ni = 0; ni < 4; ++ni)
                acc[mi][ni] = mfma16(a[mi], b[ni], acc[mi][ni]);
    }
    if (n0 < D_MODEL) {
        #pragma unroll
        for (int mi = 0; mi < 4; ++mi)
            #pragma unroll
            for (int ni = 0; ni < 4; ++ni)
                #pragma unroll
                for (int r = 0; r < 4; ++r)
                    Cq[(size_t)(m0 + wr + mi*16 + lg*4 + r) * D_MODEL + n0 + wc + ni*16 + lq] =
                        f32_to_bf16(acc[mi][ni][r]);
    } else if (n0 < D_MODEL + D_KV) {
        const int col = n0 - D_MODEL;
        #pragma unroll
        for (int mi = 0; mi < 4; ++mi)
            #pragma unroll
            for (int ni = 0; ni < 4; ++ni)
                #pragma unroll
                for (int r = 0; r < 4; ++r)
                    Ck[(size_t)(m0 + wr + mi*16 + lg*4 + r) * D_KV + col + wc + ni*16 + lq] =
                        f32_to_bf16(acc[mi][ni][r]);
    } else {
        const int cbase = n0 - (D_MODEL + D_KV);
        #pragma unroll
        for (int mi = 0; mi < 4; ++mi) {
            int row = m0 + wr + mi*16 + lg*4;     // 4 consecutive seq rows
            int bb  = row >> 11;
            int seq = row & (SEQ - 1);
            #pragma unroll
            for (int ni = 0; ni < 4; ++ni) {
                int col = cbase + wc + ni*16 + lq;
                union { u16 h[4]; uint2 d; } t;
                #pragma unroll
                for (int r = 0; r < 4; ++r) t.h[r] = f32_to_bf16(acc[mi][ni][r]);
                *(uint2*)(Vt + ((size_t)(bb * D_KV + col)) * SEQ + seq) = t.d;
            }
        }
    }
}

// ---------------------------------------------------------------------------
// Flash attention v6.1 (r11 loop structure): 64 q-rows/wave (2 B-frag
// groups), 2-buffer __syncthreads staging, no-max exp2 softmax, permlane
// exchange. lsum now accumulated on VALU (2 scalars/thread, shfl_xor(32) at
// end) instead of ones-MFMA — frees 32 AGPRs + 8 mfma32/tile.
// ---------------------------------------------------------------------------
#define PACK_P(sc0, sc1, pf)  do {                                          \
    u32 Wp[8][2];                                                           \
    _Pragma("unroll")                                                       \
    for (int q = 0; q < 4; ++q) {                                           \
        Wp[q][0]   = cvt_pk_bf16(sc0[4*q],   sc0[4*q+1]);                   \
        Wp[q][1]   = cvt_pk_bf16(sc0[4*q+2], sc0[4*q+3]);                   \
        Wp[4+q][0] = cvt_pk_bf16(sc1[4*q],   sc1[4*q+1]);                   \
        Wp[4+q][1] = cvt_pk_bf16(sc1[4*q+2], sc1[4*q+3]);                   \
    }                                                                       \
    _Pragma("unroll")                                                       \
    for (int s = 0; s < 4; ++s) {                                           \
        const int b0 = (s >> 1)*4 + 2*(s & 1);                              \
        u32 a0 = Wp[b0][0], c0 = Wp[b0+1][0];                               \
        u32 a1 = Wp[b0][1], c1 = Wp[b0+1][1];                               \
        asm("v_permlane32_swap_b32 %0, %1" : "+v"(a0), "+v"(c0));           \
        asm("v_permlane32_swap_b32 %0, %1" : "+v"(a1), "+v"(c1));           \
        pf[s].w[0] = a0; pf[s].w[1] = a1;                                   \
        pf[s].w[2] = c0; pf[s].w[3] = c1;                                   \
    }                                                                       \
} while (0)

__global__ __launch_bounds__(256, 2) void attn_mfma(const u16* __restrict__ qb,
                                                    const u16* __restrict__ kb,
                                                    const u16* __restrict__ vtb,
                                                    float* __restrict__ out,
                                                    const float* __restrict__ mw) {
    __shared__ __align__(16) u16 Ks [2][4096];   // [64 key][64 dim], XOR-swizzled
    __shared__ __align__(16) u16 VTs[2][4096];   // [64 dim][64 key], XOR-swizzled
    const int tid = threadIdx.x, lane = tid & 63, wid = tid >> 6;
    const int lq = lane & 31, hl = lane >> 5;
    // XCD swizzle: 512 blocks = 8 XCDs x 64; qtile fastest within a chunk
    const int swz   = (blockIdx.x & 7) * 64 + (blockIdx.x >> 3);
    const int qtile = swz & 31;
    const int bh    = swz >> 5;
    const int b = bh >> 3, h = bh & 7;
    const int s0 = qtile * 64;
    const int qcol = wid * D_KV + h * D_HEAD;     // nq = wid
    const size_t rowbase = (size_t)b * SEQ;

    // Q B-frags, two 32-row groups, pre-scaled by 0.125*log2(e)
    bf16x8 qA[4], qB[4];
    {
        const float C = 0.18033688011112042f;
        const u16* qsA = qb + (rowbase + s0 + lq)      * D_MODEL + qcol + 8*hl;
        const u16* qsB = qb + (rowbase + s0 + 32 + lq) * D_MODEL + qcol + 8*hl;
        #pragma unroll
        for (int s = 0; s < 4; ++s) {
            bf16x8 ta = *(const bf16x8*)(qsA + 16*s);
            bf16x8 tb = *(const bf16x8*)(qsB + 16*s);
            #pragma unroll
            for (int e = 0; e < 8; ++e) {
                ta[e] = (short)f32_to_bf16(bf16_to_f32((u16)ta[e]) * C);
                tb[e] = (short)f32_to_bf16(bf16_to_f32((u16)tb[e]) * C);
            }
            qA[s] = ta; qB[s] = tb;
        }
    }

    // staging source offsets (pre-swizzled so LDS dest stays linear)
    const char* kbase = (const char*)(kb + rowbase * D_KV + h * D_HEAD);
    const char* vbase = (const char*)(vtb + ((size_t)b * D_KV + h * D_HEAD) * SEQ);
    int ksrc_off[2], vsrc_off[2];
    #pragma unroll
    for (int c = 0; c < 2; ++c) {
        int o   = c*4096 + tid*16;
        int row = o >> 7;
        int col = (o & 127) ^ ((row & 7) << 4);
        ksrc_off[c] = row*(D_KV*2) + col;       // K row stride 1024 B
        vsrc_off[c] = row*(SEQ*2) + col;        // VT row stride 4096 B
    }

    f32x16 o0A = {}, o1A = {}, o0B = {}, o1B = {};
    float lsA = 0.f, lsB = 0.f;                 // per-lane lsum partials

    const int NT = SEQ / 64;
    #pragma unroll
    for (int c = 0; c < 2; ++c) {               // prologue: tile 0 -> buf 0
        load_lds16(kbase + ksrc_off[c], (char*)Ks[0]  + c*4096 + tid*16);
        load_lds16(vbase + vsrc_off[c], (char*)VTs[0] + c*4096 + tid*16);
    }

    const int swl = (lq & 7) << 4;
    for (int j = 0; j < NT; ++j) {
        const int buf = j & 1;
        __syncthreads();                        // drains staged loads + joins
        if (j + 1 < NT) {
            const char* kj = kbase + (size_t)(j+1)*64*(D_KV*2);
            const char* vj = vbase + (size_t)(j+1)*128;
            #pragma unroll
            for (int c = 0; c < 2; ++c) {
                load_lds16(kj + ksrc_off[c], (char*)Ks[buf^1]  + c*4096 + tid*16);
                load_lds16(vj + vsrc_off[c], (char*)VTs[buf^1] + c*4096 + tid*16);
            }
        }

        // ---- QK^T: each K-frag read feeds both q-groups ----
        f32x16 sA0 = {}, sA1 = {}, sB0 = {}, sB1 = {};
        const char* Kc = (const char*)Ks[buf];
        __builtin_amdgcn_s_setprio(1);
        #pragma unroll
        for (int s = 0; s < 4; ++s) {
            int col = 32*s + 16*hl;
            bf16x8 k0 = *(const bf16x8*)(Kc + (( lq      *128 + col) ^ swl));
            bf16x8 k1 = *(const bf16x8*)(Kc + (((lq + 32)*128 + col) ^ swl));
            sA0 = mfma32(k0, qA[s], sA0);
            sB0 = mfma32(k0, qB[s], sB0);
            sA1 = mfma32(k1, qA[s], sA1);
            sB1 = mfma32(k1, qB[s], sB1);
        }
        __builtin_amdgcn_s_setprio(0);

        // ---- P = 2^sc (no max; range-safe) + VALU lsum partials ----
        float tA = 0.f, tB = 0.f;
        #pragma unroll
        for (int i = 0; i < 16; ++i) { sA0[i] = exp2_fast(sA0[i]); tA += sA0[i]; }
        #pragma unroll
        for (int i = 0; i < 16; ++i) { sA1[i] = exp2_fast(sA1[i]); tA += sA1[i]; }
        #pragma unroll
        for (int i = 0; i < 16; ++i) { sB0[i] = exp2_fast(sB0[i]); tB += sB0[i]; }
        #pragma unroll
        for (int i = 0; i < 16; ++i) { sB1[i] = exp2_fast(sB1[i]); tB += sB1[i]; }
        lsA += tA; lsB += tB;

        Frag pfA[4], pfB[4];
        PACK_P(sA0, sA1, pfA);
        PACK_P(sB0, sB1, pfB);

        // ---- PV: each V-frag read feeds both q-groups ----
        const char* Vc = (const char*)VTs[buf];
        __builtin_amdgcn_s_setprio(1);
        #pragma unroll
        for (int s = 0; s < 4; ++s) {
            int col = 32*s + 16*hl;
            bf16x8 v0 = *(const bf16x8*)(Vc + (( lq      *128 + col) ^ swl));
            bf16x8 v1 = *(const bf16x8*)(Vc + (((lq + 32)*128 + col) ^ swl));
            o0A = mfma32(v0, pfA[s].v, o0A);
            o0B = mfma32(v0, pfB[s].v, o0B);
            o1A = mfma32(v1, pfA[s].v, o1A);
            o1B = mfma32(v1, pfB[s].v, o1B);
        }
        __builtin_amdgcn_s_setprio(0);
    }

    // ---- epilogue: fold lane-partner lsum halves, normalize, store ----
    float lA = lsA + __shfl_xor(lsA, 32);
    float lB = lsB + __shfl_xor(lsB, 32);
    const float w = 1.f / (1.f + __expf(-mw[0]));
    const float invA = (1.f - w) / lA;
    const float invB = (1.f - w) / lB;
    float* dstA = out + (rowbase + s0 + lq)      * D_MODEL + qcol;
    float* dstB = out + (rowbase + s0 + 32 + lq) * D_MODEL + qcol;
    #pragma unroll
    for (int g = 0; g < 4; ++g) {
        int dbase = 8*g + 4*hl;
        *(float4*)(dstA + dbase) =
            make_float4(o0A[4*g]*invA, o0A[4*g+1]*invA, o0A[4*g+2]*invA, o0A[4*g+3]*invA);
        *(float4*)(dstA + 32 + dbase) =
            make_float4(o1A[4*g]*invA, o1A[4*g+1]*invA, o1A[4*g+2]*invA, o1A[4*g+3]*invA);
        *(float4*)(dstB + dbase) =
            make_float4(o0B[4*g]*invB, o0B[4*g+1]*invB, o0B[4*g+2]*invB, o0B[4*g+3]*invB);
        *(float4*)(dstB + 32 + dbase) =
            make_float4(o1B[4*g]*invB, o1B[4*g+1]*invB, o1B[4*g+2]*invB, o1B[4*g+3]*invB);
    }
}

// ---------------------------------------------------------------------------
// out[i][j] += w * (elu(q) @ memT^T)[i][j] / den[i], den fused during staging.
// ---------------------------------------------------------------------------
__global__ __launch_bounds__(256) void mem_gemm_mfma(const u16* __restrict__ qbuf,
                                                     const u16* __restrict__ MT,
                                                     const float* __restrict__ mn,
                                                     float* __restrict__ out,
                                                     const float* __restrict__ mw) {
    __shared__ __align__(16) u16 As[128*32];
    __shared__ __align__(16) u16 Bs[128*32];
    __shared__ float den_s[128];
    const int tid  = threadIdx.x;
    const int lane = tid & 63;
    const int wid  = tid >> 6;
    const int i0 = blockIdx.y * 128, n0 = blockIdx.x * 128;
    const int wr = (wid >> 1) * 64, wc = (wid & 1) * 64;
    const int lq = lane & 15, lg = lane >> 4;
    const int srow = tid >> 2;
    const int scol = (tid & 3) * 8;
    f32x4 acc[4][4] = {};
    float dpart0 = 0.f, dpart1 = 0.f;
    const u16* Bg = MT + (size_t)(n0 + srow) * D_KV + scol;
    for (int k0 = 0; k0 < D_KV; k0 += 32) {
        __syncthreads();
        float4 mn0 = *(const float4*)(mn + k0 + scol);
        float4 mn1 = *(const float4*)(mn + k0 + scol + 4);
        float mnr[8] = {mn0.x, mn0.y, mn0.z, mn0.w, mn1.x, mn1.y, mn1.z, mn1.w};
        #pragma unroll
        for (int half = 0; half < 2; ++half) {
            int row = half*64 + srow;
            bf16x8 v = *(const bf16x8*)(qbuf + (size_t)(i0 + row) * D_KV + k0 + scol);
            bf16x8 ov;
            float dp = 0.f;
            #pragma unroll
            for (int e = 0; e < 8; ++e) {
                float xv = bf16_to_f32((u16)v[e]);
                float el = xv > 0.f ? xv : __expf(xv) - 1.f;
                dp += el * mnr[e];
                ov[e] = (short)f32_to_bf16(el);
            }
            if (half) dpart1 += dp; else dpart0 += dp;
            *(bf16x8*)&As[row*32 + scol] = ov;
        }
        load_lds16(Bg + k0,                     &Bs[srow*32 + scol]);
        load_lds16(Bg + k0 + (size_t)64*D_KV,   &Bs[(srow+64)*32 + scol]);
        __syncthreads();
        bf16x8 a[4], b[4];
        #pragma unroll
        for (int mi = 0; mi < 4; ++mi)
            a[mi] = *(const bf16x8*)&As[(wr + mi*16 + lq)*32 + lg*8];
        #pragma unroll
        for (int ni = 0; ni < 4; ++ni)
            b[ni] = *(const bf16x8*)&Bs[(wc + ni*16 + lq)*32 + lg*8];
        #pragma unroll
        for (int mi = 0; mi < 4; ++mi)
            #pragma unroll
            for (int ni = 0; ni < 4; ++ni)
                acc[mi][ni] = mfma16(a[mi], b[ni], acc[mi][ni]);
    }
    // fold the 4 staging lanes (tid&3 = col quarters) of each row
    dpart0 += __shfl_xor(dpart0, 1);  dpart0 += __shfl_xor(dpart0, 2);
    dpart1 += __shfl_xor(dpart1, 1);  dpart1 += __shfl_xor(dpart1, 2);
    if ((tid & 3) == 0) { den_s[srow] = dpart0; den_s[srow + 64] = dpart1; }
    __syncthreads();
    const float w = 1.f / (1.f + __expf(-mw[0]));
    #pragma unroll
    for (int mi = 0; mi < 4; ++mi)
        #pragma unroll
        for (int r = 0; r < 4; ++r) {
            int rl  = wr + mi*16 + lg*4 + r;
            float g = w / den_s[rl];
            int row = i0 + rl;
            #pragma unroll
            for (int ni = 0; ni < 4; ++ni) {
                float* dst = out + (size_t)row * D_KV + n0 + wc + ni*16 + lq;
                *dst += acc[mi][ni][r] * g;
            }
        }
}

// ---------------------------------------------------------------------------
extern "C" void kernel_launch(void* const* d_in, const int* in_sizes, int n_in,
                              void* d_out, int out_size, void* d_ws, size_t ws_size,
                              hipStream_t stream) {
    const float* x   = (const float*)d_in[0];
    const float* Wq  = (const float*)d_in[1];
    const float* Wk  = (const float*)d_in[2];
    const float* Wv  = (const float*)d_in[3];
    const float* mem = (const float*)d_in[4];
    const float* mn  = (const float*)d_in[5];
    const float* mw  = (const float*)d_in[6];
    float* out = (float*)d_out;

    u16* qb  = (u16*)d_ws;                               // [4096,2048] bf16
    u16* kb  = qb  + (size_t)BS * D_MODEL;               // [4096,512] K
    u16* xb  = kb  + (size_t)BS * D_KV;                  // [4096,2048]
    u16* vtb = xb  + (size_t)BS * D_MODEL;               // [2,512,2048] V^T
    u16* mtb = vtb + (size_t)BATCH * D_KV * SEQ;         // [512,512] memT
    // Wq|Wk|Wv bf16 (12.6 MB) lives in d_out scratch; consumed by the qkv
    // gemm, then attn fully overwrites all of d_out. Deterministic.
    u16* wf  = (u16*)d_out;

    prep<<<2304, 256, 0, stream>>>(x, xb,
                                   Wq, wf,
                                   Wk, wf + (size_t)D_MODEL*D_MODEL,
                                   Wv, wf + (size_t)(D_MODEL+D_KV)*D_MODEL,
                                   mem, mtb);
    gemm_qkv<<<dim3(NQKV/128, BS/128), 256, 0, stream>>>(xb, wf, qb, kb, vtb);
    attn_mfma<<<dim3(SEQ/64 * BATCH*N_HEAD), 256, 0, stream>>>(qb, kb, vtb, out, mw);
    mem_gemm_mfma<<<dim3(D_KV/128, MROWS/128), 256, 0, stream>>>(qb, mtb, mn, out, mw);
}